// Round 8
// baseline (52.369 us; speedup 1.0000x reference)
//
#include <hip/hip_runtime.h>
#include <type_traits>

typedef __attribute__((ext_vector_type(4))) float f32x4;
typedef __attribute__((ext_vector_type(8))) short s16x8;

__device__ __forceinline__ unsigned short f2bf(float f) {
    unsigned int u = __builtin_bit_cast(unsigned int, f);
    u += 0x7fffu + ((u >> 16) & 1u);           // round-to-nearest-even
    return (unsigned short)(u >> 16);
}

// packed f32x2 -> bf16x2 (RNE), one HW instr
__device__ __forceinline__ unsigned cvtpk(float lo, float hi) {
    unsigned r;
    asm("v_cvt_pk_bf16_f32 %0, %1, %2" : "=v"(r) : "v"(lo), "v"(hi));
    return r;
}

__device__ __forceinline__ void gload_lds16(const void* g, void* l) {
    __builtin_amdgcn_global_load_lds(
        (const __attribute__((address_space(1))) void*)g,
        (__attribute__((address_space(3))) void*)l, 16, 0, 0);
}

// ---------------------------------------------------------------------------
// LDS tile section (bf16, 64 k-elems = 128 B per row):
//   byte(row, chunk) = row*128 + ((chunk ^ (row&7)) << 4)
// ---------------------------------------------------------------------------
template<int ROWS>
__device__ __forceinline__ void stage_lds(const unsigned short* __restrict__ src,
                                          int ld, int row0, int k0, int maxRowExcl,
                                          char* lds, int wid, int lane) {
    const int subrow = lane >> 3;            // 0..7
    const int gchunk = (lane & 7) ^ subrow;  // inverse swizzle on source
    #pragma unroll
    for (int p = 0; p < (ROWS + 31) / 32; ++p) {
        const int r0 = (p * 4 + wid) * 8;    // 8 rows / wave-call
        int gr = row0 + r0 + subrow;
        if (gr >= maxRowExcl) gr = maxRowExcl - 1;
        const char* g = (const char*)(src + (size_t)gr * ld + k0) + gchunk * 16;
        gload_lds16(g, lds + r0 * 128);      // wave-uniform base + lane*16
    }
}

template<int MF, int NF>
__device__ __forceinline__ void mfma_all(const s16x8 (&af)[2][MF], const s16x8 (&bfr)[2][NF],
                                         f32x4 (&acc)[MF][NF]) {
    #pragma unroll
    for (int kk = 0; kk < 2; ++kk)
        #pragma unroll
        for (int mi = 0; mi < MF; ++mi)
            #pragma unroll
            for (int ni = 0; ni < NF; ++ni)
                acc[mi][ni] = __builtin_amdgcn_mfma_f32_16x16x32_bf16(
                    af[kk][mi], bfr[kk][ni], acc[mi][ni], 0, 0, 0);
}

// One BK=64 step from LDS (A) + LDS (B), T5 setprio around the MFMA cluster.
template<int MF, int NF>
__device__ __forceinline__ void compute_step(const char* As, const char* Bs,
                                             int arow_base, int brow_base,
                                             int lr, int lg, f32x4 (&acc)[MF][NF]) {
    s16x8 af[2][MF], bfr[2][NF];
    #pragma unroll
    for (int kk = 0; kk < 2; ++kk) {
        const int chunk = kk * 4 + lg;
        #pragma unroll
        for (int f = 0; f < MF; ++f) {
            const int row = arow_base + f * 16 + lr;
            af[kk][f] = *reinterpret_cast<const s16x8*>(As + row * 128 + ((chunk ^ (row & 7)) << 4));
        }
        #pragma unroll
        for (int f = 0; f < NF; ++f) {
            const int row = brow_base + f * 16 + lr;
            bfr[kk][f] = *reinterpret_cast<const s16x8*>(Bs + row * 128 + ((chunk ^ (row & 7)) << 4));
        }
    }
    __builtin_amdgcn_s_setprio(1);
    mfma_all<MF, NF>(af, bfr, acc);
    __builtin_amdgcn_s_setprio(0);
}

__device__ __forceinline__ int xcd_swizzle(int bid, int nwg) {
    const int q = nwg >> 3, r = nwg & 7;
    const int xcd = bid & 7, idx = bid >> 3;
    return (xcd < r ? xcd * (q + 1) : r * (q + 1) + (xcd - r) * q) + idx;
}

// ---------------------------------------------------------------------------
// K1: fused prep+GEMM1.  C1[512,512] = bf16( x[512,1024]f32 @ W[1024,512]f32 )
// In-kernel cvt (v_cvt_pk) + W-transpose via ds_write addressing. Tile 32x32,
// 256 blocks (all CUs), BK=128/phase (2 sections), 8 phases, T14 dbuf.
// ---------------------------------------------------------------------------
__global__ __launch_bounds__(256) void fused_g1(const float* __restrict__ x,
                                                const float* __restrict__ W,
                                                unsigned short* __restrict__ C1) {
    constexpr int SEC = 4096;                  // one 64-k section: 32 rows * 128 B
    constexpr int PBUF = 4 * SEC;              // phase buf: A(2 sec) + B(2 sec)
    __shared__ __align__(16) char lds[2 * PBUF];   // 32 KiB

    const int bid = xcd_swizzle((int)blockIdx.x, 256);
    const int m0 = (bid & 15) * 32, n0 = (bid >> 4) * 32;

    const int tid = threadIdx.x, lane = tid & 63, wid = tid >> 6;
    const int wm = wid >> 1, wn = wid & 1;
    const int arow_base = wm * 16, brow_base = wn * 16;
    const int lr = lane & 15, lg = lane >> 4;

    const int rowA = tid >> 3, ksA = (tid & 7) * 16;   // A: 32 rows x 16 k / thread
    const int nB = tid & 31,  ksB = (tid >> 5) * 16;   // B: 32 cols x 16 k / thread

    f32x4 acc = {0.f, 0.f, 0.f, 0.f};
    f32x4 va[4];
    float wb[16];

    auto loadPh = [&](int k0) {
        const float* pa = x + (size_t)(m0 + rowA) * 1024 + k0 + ksA;
        #pragma unroll
        for (int i = 0; i < 4; ++i) va[i] = *reinterpret_cast<const f32x4*>(pa + i * 4);
        #pragma unroll
        for (int i = 0; i < 16; ++i) wb[i] = W[(size_t)(k0 + ksB + i) * 512 + n0 + nB];
    };
    auto writePh = [&](char* buf) {
        uint4 u0 = { cvtpk(va[0].x,va[0].y), cvtpk(va[0].z,va[0].w),
                     cvtpk(va[1].x,va[1].y), cvtpk(va[1].z,va[1].w) };
        uint4 u1 = { cvtpk(va[2].x,va[2].y), cvtpk(va[2].z,va[2].w),
                     cvtpk(va[3].x,va[3].y), cvtpk(va[3].z,va[3].w) };
        {
            const int sec = ksA >> 6, cin = (ksA & 63) >> 3;
            char* base = buf + sec * SEC + rowA * 128;
            *reinterpret_cast<uint4*>(base + ((( cin    ) ^ (rowA & 7)) << 4)) = u0;
            *reinterpret_cast<uint4*>(base + (((cin + 1) ^ (rowA & 7)) << 4)) = u1;
        }
        uint4 w0 = { cvtpk(wb[0],wb[1]),  cvtpk(wb[2],wb[3]),
                     cvtpk(wb[4],wb[5]),  cvtpk(wb[6],wb[7]) };
        uint4 w1 = { cvtpk(wb[8],wb[9]),  cvtpk(wb[10],wb[11]),
                     cvtpk(wb[12],wb[13]), cvtpk(wb[14],wb[15]) };
        {
            const int sec = ksB >> 6, cin = (ksB & 63) >> 3;
            char* base = buf + 2 * SEC + sec * SEC + nB * 128;
            *reinterpret_cast<uint4*>(base + ((( cin    ) ^ (nB & 7)) << 4)) = w0;
            *reinterpret_cast<uint4*>(base + (((cin + 1) ^ (nB & 7)) << 4)) = w1;
        }
    };

    loadPh(0);
    writePh(lds);
    __syncthreads();

    #pragma unroll 1
    for (int ph = 0; ph < 8; ++ph) {
        char* cur = lds + (ph & 1) * PBUF;
        char* nxt = lds + ((ph + 1) & 1) * PBUF;
        if (ph < 7) loadPh((ph + 1) * 128);            // loads in flight over compute
        #pragma unroll
        for (int sec = 0; sec < 2; ++sec) {
            const char* As = cur + sec * SEC;
            const char* Bs = cur + 2 * SEC + sec * SEC;
            #pragma unroll
            for (int kk = 0; kk < 2; ++kk) {
                const int c = kk * 4 + lg;
                const int ra = arow_base + lr, rb = brow_base + lr;
                s16x8 a = *reinterpret_cast<const s16x8*>(As + ra * 128 + ((c ^ (ra & 7)) << 4));
                s16x8 b = *reinterpret_cast<const s16x8*>(Bs + rb * 128 + ((c ^ (rb & 7)) << 4));
                acc = __builtin_amdgcn_mfma_f32_16x16x32_bf16(a, b, acc, 0, 0, 0);
            }
        }
        if (ph < 7) writePh(nxt);                      // cvt+ds_write late (T14)
        __syncthreads();
    }

    const int gcol = n0 + brow_base + lr;              // C/D: col=lane&15 [m89]
    const int grow0 = m0 + arow_base + lg * 4;
    #pragma unroll
    for (int r = 0; r < 4; ++r)
        C1[(size_t)(grow0 + r) * 512 + gcol] = f2bf(acc[r]);
}

// ---------------------------------------------------------------------------
// K2 (x2, diagnostic): GEMM2  out[512,20000] = C1 @ E^T (f32). Tile 128x160,
// BK=64, 8 K-steps.  A: global_load_lds.  B: coalesced f32 global -> regs ->
// cvt_pk -> ds_write (T14). One raw s_barrier per K-step, counted vmcnt.
// Grid 504 = 8 XCDs x {63,63,63,63,62,62,62,62}; LDS 72 KiB -> 2 blocks/CU.
// ---------------------------------------------------------------------------
__global__ __launch_bounds__(256, 2) void gemm2fused(const unsigned short* __restrict__ C1,
                                                     const float* __restrict__ E,
                                                     float* __restrict__ out) {
    constexpr int MF = 4, NF = 5, BM = 128, BN = 160;
    constexpr int M = 512, N = 20000, K = 512, NSTEP = K / 64;
    constexpr int ABUF = BM * 128;                 // 16384
    constexpr int BUF = (BM + BN) * 128;           // 36864
    __shared__ __align__(16) char lds[2 * BUF];    // 72 KiB

    const int xcd = (int)blockIdx.x & 7, idx = (int)blockIdx.x >> 3;
    if (xcd >= 4 && idx >= 62) return;
    const int nb = (xcd < 4 ? xcd * 63 : 252 + (xcd - 4) * 62) + idx;
    const int m0 = (nb & 3) * BM;                  // 4 consecutive nb share E panel
    const int n0 = (nb >> 2) * BN;

    const int tid = threadIdx.x, lane = tid & 63, wid = tid >> 6;
    const int wm = wid >> 1, wn = wid & 1;
    const int arow_base = wm * (16 * MF);          // 0 / 64
    const int brow_base = wn * (16 * NF);          // 0 / 80
    const int lr = lane & 15, lg = lane >> 4;

    const int r_in = tid >> 4, c4 = tid & 15;

    f32x4 acc[MF][NF] = {};
    f32x4 breg[10];

    auto loadB = [&](int k0) {
        #pragma unroll
        for (int p = 0; p < 10; ++p)
            breg[p] = *reinterpret_cast<const f32x4*>(
                E + (size_t)(n0 + p * 16 + r_in) * 512 + k0 + c4 * 4);
    };
    auto writeB = [&](char* Bs) {
        #pragma unroll
        for (int p = 0; p < 10; ++p) {
            const int row = p * 16 + r_in;
            const unsigned lo = cvtpk(breg[p].x, breg[p].y);
            const unsigned hi = cvtpk(breg[p].z, breg[p].w);
            const int byte = row * 128 + ((((c4 >> 1)) ^ (row & 7)) << 4) + (c4 & 1) * 8;
            *reinterpret_cast<uint2*>(Bs + byte) = make_uint2(lo, hi);
        }
    };

    loadB(0);                                       // vm: B0=10
    stage_lds<BM>(C1, K, m0, 0, M, lds, wid, lane); // vm: +A0=4 -> 14
    writeB(lds + ABUF);

    #pragma unroll 1
    for (int t = 0; t < NSTEP; ++t) {
        char* cur = lds + (t & 1) * BUF;
        char* nxt = lds + ((t + 1) & 1) * BUF;
        if (t < NSTEP - 1) {
            loadB((t + 1) * 64);                    // B(t+1) regs, in flight
            asm volatile("s_waitcnt vmcnt(10)" ::: "memory");   // A(t) landed
        } else {
            asm volatile("s_waitcnt vmcnt(0)" ::: "memory");
        }
        asm volatile("s_waitcnt lgkmcnt(0)" ::: "memory");      // publish ds_writes
        __builtin_amdgcn_s_barrier();               // tile t complete; nxt free
        if (t < NSTEP - 1)
            stage_lds<BM>(C1, K, m0, (t + 1) * 64, M, nxt, wid, lane);  // A(t+1)
        compute_step<MF, NF>(cur, cur + ABUF, arow_base, brow_base, lr, lg, acc);
        if (t < NSTEP - 1)
            writeB(nxt + ABUF);                     // cvt+write B(t+1) (late, T14)
    }

    #pragma unroll
    for (int mi = 0; mi < MF; ++mi)
        #pragma unroll
        for (int ni = 0; ni < NF; ++ni) {
            const int gcol = n0 + brow_base + ni * 16 + lr;
            const int grow0 = m0 + arow_base + mi * 16 + lg * 4;
            #pragma unroll
            for (int r = 0; r < 4; ++r)
                out[(size_t)(grow0 + r) * N + gcol] = acc[mi][ni][r];
        }
}

// ---------------------------------------------------------------------------

extern "C" void kernel_launch(void* const* d_in, const int* in_sizes, int n_in,
                              void* d_out, int out_size, void* d_ws, size_t ws_size,
                              hipStream_t stream) {
    const float* x = (const float*)d_in[0];     // [512,1024]
    const float* E = (const float*)d_in[1];     // [20000,512]
    const float* W = (const float*)d_in[2];     // [1024,512]
    float* out = (float*)d_out;                 // [512,20000]

    unsigned short* C1 = (unsigned short*)d_ws; // 512 KiB

    // K1: fused prep + GEMM1 (reads x, W f32 directly)
    fused_g1<<<256, 256, 0, stream>>>(x, W, C1);

    // K2 x2: identical idempotent launches — 2nd is a timing diagnostic
    // (dur_new - dur_old + ~3 us  =>  gemm2fused's true duration).
    gemm2fused<<<504, 256, 0, stream>>>(C1, E, out);
    gemm2fused<<<504, 256, 0, stream>>>(C1, E, out);
}

// Round 9
// 32.284 us; speedup vs baseline: 1.6221x; 1.6221x over previous
//
#include <hip/hip_runtime.h>
#include <type_traits>

typedef __attribute__((ext_vector_type(4))) float f32x4;
typedef __attribute__((ext_vector_type(8))) short s16x8;

__device__ __forceinline__ unsigned short f2bf(float f) {
    unsigned int u = __builtin_bit_cast(unsigned int, f);
    u += 0x7fffu + ((u >> 16) & 1u);           // round-to-nearest-even
    return (unsigned short)(u >> 16);
}

// packed f32x2 -> bf16x2 (RNE), one HW instr
__device__ __forceinline__ unsigned cvtpk(float lo, float hi) {
    unsigned r;
    asm("v_cvt_pk_bf16_f32 %0, %1, %2" : "=v"(r) : "v"(lo), "v"(hi));
    return r;
}

__device__ __forceinline__ void gload_lds16(const void* g, void* l) {
    __builtin_amdgcn_global_load_lds(
        (const __attribute__((address_space(1))) void*)g,
        (__attribute__((address_space(3))) void*)l, 16, 0, 0);
}

// ---------------------------------------------------------------------------
// LDS tile section (bf16, 64 k-elems = 128 B per row):
//   byte(row, chunk) = row*128 + ((chunk ^ (row&7)) << 4)
// Staged via global_load_lds: linear LDS dest, pre-swizzled source chunk.
// ---------------------------------------------------------------------------
template<int ROWS, int WAVES>
__device__ __forceinline__ void stage_lds(const unsigned short* __restrict__ src,
                                          int ld, int row0, int k0,
                                          char* lds, int wid, int lane) {
    const int subrow = lane >> 3;            // 0..7
    const int gchunk = (lane & 7) ^ subrow;  // inverse swizzle on source
    #pragma unroll
    for (int p = 0; p < ROWS / (WAVES * 8); ++p) {
        const int r0 = (p * WAVES + wid) * 8;
        const int gr = row0 + r0 + subrow;
        const char* g = (const char*)(src + (size_t)gr * ld + k0) + gchunk * 16;
        gload_lds16(g, lds + r0 * 128);      // wave-uniform base + lane*16
    }
}

__device__ __forceinline__ int xcd_swizzle(int bid, int nwg) {
    const int q = nwg >> 3, r = nwg & 7;
    const int xcd = bid & 7, idx = bid >> 3;
    return (xcd < r ? xcd * (q + 1) : r * (q + 1) + (xcd - r) * q) + idx;
}

// ---------------------------------------------------------------------------
// K1: fused prep+GEMM1.  C1[512,512] = bf16( x[512,1024]f32 @ W[1024,512]f32 )
// In-kernel cvt (v_cvt_pk) + W-transpose via ds_write addressing. Tile 32x32,
// 256 blocks (all CUs), BK=128/phase (2 sections), 8 phases, T14 dbuf.
// ---------------------------------------------------------------------------
__global__ __launch_bounds__(256) void fused_g1(const float* __restrict__ x,
                                                const float* __restrict__ W,
                                                unsigned short* __restrict__ C1) {
    constexpr int SEC = 4096;                  // one 64-k section: 32 rows * 128 B
    constexpr int PBUF = 4 * SEC;              // phase buf: A(2 sec) + B(2 sec)
    __shared__ __align__(16) char lds[2 * PBUF];   // 32 KiB

    const int bid = xcd_swizzle((int)blockIdx.x, 256);
    const int m0 = (bid & 15) * 32, n0 = (bid >> 4) * 32;

    const int tid = threadIdx.x, lane = tid & 63, wid = tid >> 6;
    const int wm = wid >> 1, wn = wid & 1;
    const int arow_base = wm * 16, brow_base = wn * 16;
    const int lr = lane & 15, lg = lane >> 4;

    const int rowA = tid >> 3, ksA = (tid & 7) * 16;   // A: 32 rows x 16 k / thread
    const int nB = tid & 31,  ksB = (tid >> 5) * 16;   // B: 32 cols x 16 k / thread

    f32x4 acc = {0.f, 0.f, 0.f, 0.f};
    f32x4 va[4];
    float wb[16];

    auto loadPh = [&](int k0) {
        const float* pa = x + (size_t)(m0 + rowA) * 1024 + k0 + ksA;
        #pragma unroll
        for (int i = 0; i < 4; ++i) va[i] = *reinterpret_cast<const f32x4*>(pa + i * 4);
        #pragma unroll
        for (int i = 0; i < 16; ++i) wb[i] = W[(size_t)(k0 + ksB + i) * 512 + n0 + nB];
    };
    auto writePh = [&](char* buf) {
        uint4 u0 = { cvtpk(va[0].x,va[0].y), cvtpk(va[0].z,va[0].w),
                     cvtpk(va[1].x,va[1].y), cvtpk(va[1].z,va[1].w) };
        uint4 u1 = { cvtpk(va[2].x,va[2].y), cvtpk(va[2].z,va[2].w),
                     cvtpk(va[3].x,va[3].y), cvtpk(va[3].z,va[3].w) };
        {
            const int sec = ksA >> 6, cin = (ksA & 63) >> 3;
            char* base = buf + sec * SEC + rowA * 128;
            *reinterpret_cast<uint4*>(base + ((( cin    ) ^ (rowA & 7)) << 4)) = u0;
            *reinterpret_cast<uint4*>(base + (((cin + 1) ^ (rowA & 7)) << 4)) = u1;
        }
        uint4 w0 = { cvtpk(wb[0],wb[1]),  cvtpk(wb[2],wb[3]),
                     cvtpk(wb[4],wb[5]),  cvtpk(wb[6],wb[7]) };
        uint4 w1 = { cvtpk(wb[8],wb[9]),  cvtpk(wb[10],wb[11]),
                     cvtpk(wb[12],wb[13]), cvtpk(wb[14],wb[15]) };
        {
            const int sec = ksB >> 6, cin = (ksB & 63) >> 3;
            char* base = buf + 2 * SEC + sec * SEC + nB * 128;
            *reinterpret_cast<uint4*>(base + ((( cin    ) ^ (nB & 7)) << 4)) = w0;
            *reinterpret_cast<uint4*>(base + (((cin + 1) ^ (nB & 7)) << 4)) = w1;
        }
    };

    loadPh(0);
    writePh(lds);
    __syncthreads();

    #pragma unroll 1
    for (int ph = 0; ph < 8; ++ph) {
        char* cur = lds + (ph & 1) * PBUF;
        char* nxt = lds + ((ph + 1) & 1) * PBUF;
        if (ph < 7) loadPh((ph + 1) * 128);            // loads in flight over compute
        #pragma unroll
        for (int sec = 0; sec < 2; ++sec) {
            const char* As = cur + sec * SEC;
            const char* Bs = cur + 2 * SEC + sec * SEC;
            #pragma unroll
            for (int kk = 0; kk < 2; ++kk) {
                const int c = kk * 4 + lg;
                const int ra = arow_base + lr, rb = brow_base + lr;
                s16x8 a = *reinterpret_cast<const s16x8*>(As + ra * 128 + ((c ^ (ra & 7)) << 4));
                s16x8 b = *reinterpret_cast<const s16x8*>(Bs + rb * 128 + ((c ^ (rb & 7)) << 4));
                acc = __builtin_amdgcn_mfma_f32_16x16x32_bf16(a, b, acc, 0, 0, 0);
            }
        }
        if (ph < 7) writePh(nxt);                      // cvt+ds_write late (T14)
        __syncthreads();
    }

    const int gcol = n0 + brow_base + lr;              // C/D: col=lane&15 [m89]
    const int grow0 = m0 + arow_base + lg * 4;
    #pragma unroll
    for (int r = 0; r < 4; ++r)
        C1[(size_t)(grow0 + r) * 512 + gcol] = f2bf(acc[r]);
}

// ---------------------------------------------------------------------------
// K2: GEMM2  out[512,20000] = C1 @ E^T (f32). Tile 128x160, BK=64, 8 K-steps.
// 512 threads = 8 waves (4m x 2n; per-wave 32x80, MF=2 NF=5) -> with 72 KiB
// LDS and <=128 VGPR this gives 2 blocks/CU = 16 waves/CU (4/SIMD), 2x the
// TLP of the 4-wave variant at identical LDS.
// A (C1 bf16): global_load_lds (2/wave/step).  B (E f32): coalesced global ->
// regs (5 dwordx4/thread) -> cvt_pk -> ds_write into freed buffer (T14).
// One raw s_barrier per K-step; counted vmcnt (B stays in flight across it).
// Ledger/iter t: entry outstanding A(t)=2; +B(t+1)=5 -> 7; vmcnt(5) drains
// A(t); lgkm(0) publishes my B(t) ds_writes; s_barrier => tile t complete,
// nxt free; +A(t+1)=2; compute cur; writeB(t+1)->nxt (compiler drains B regs).
// Grid 504 = 8 XCDs x {63,63,63,63,62,62,62,62}; 20000 = 125*160, no N edge.
// ---------------------------------------------------------------------------
__global__ __launch_bounds__(512, 4) void gemm2fused(const unsigned short* __restrict__ C1,
                                                     const float* __restrict__ E,
                                                     float* __restrict__ out) {
    constexpr int MF = 2, NF = 5, BM = 128, BN = 160;
    constexpr int N = 20000, K = 512, NSTEP = K / 64;
    constexpr int ABUF = BM * 128;                 // 16384
    constexpr int BUF = (BM + BN) * 128;           // 36864
    __shared__ __align__(16) char lds[2 * BUF];    // 72 KiB

    const int xcd = (int)blockIdx.x & 7, idx = (int)blockIdx.x >> 3;
    if (xcd >= 4 && idx >= 62) return;
    const int nb = (xcd < 4 ? xcd * 63 : 252 + (xcd - 4) * 62) + idx;
    const int m0 = (nb & 3) * BM;                  // 4 consecutive nb share E panel
    const int n0 = (nb >> 2) * BN;

    const int tid = threadIdx.x, lane = tid & 63, wid = tid >> 6;  // 0..7
    const int wm = wid >> 1, wn = wid & 1;         // 4 x 2 wave grid
    const int arow_base = wm * 32;                 // 0/32/64/96
    const int brow_base = wn * 80;                 // 0/80
    const int lr = lane & 15, lg = lane >> 4;

    const int r_in = tid >> 4, c4 = tid & 15;      // B stage: 32 row-slots x 16

    f32x4 acc[MF][NF] = {};
    f32x4 breg[5];

    auto loadB = [&](int k0) {
        #pragma unroll
        for (int p = 0; p < 5; ++p)
            breg[p] = *reinterpret_cast<const f32x4*>(
                E + (size_t)(n0 + p * 32 + r_in) * 512 + k0 + c4 * 4);
    };
    auto writeB = [&](char* Bs) {
        #pragma unroll
        for (int p = 0; p < 5; ++p) {
            const int row = p * 32 + r_in;
            const unsigned lo = cvtpk(breg[p].x, breg[p].y);
            const unsigned hi = cvtpk(breg[p].z, breg[p].w);
            const int byte = row * 128 + (((c4 >> 1) ^ (row & 7)) << 4) + (c4 & 1) * 8;
            *reinterpret_cast<uint2*>(Bs + byte) = make_uint2(lo, hi);
        }
    };

    loadB(0);                                          // vm: B0=5
    stage_lds<BM, 8>(C1, K, m0, 0, lds, wid, lane);    // vm: +A0=2 -> 7
    writeB(lds + ABUF);                                // compiler waits breg only

    #pragma unroll 1
    for (int t = 0; t < NSTEP; ++t) {
        char* cur = lds + (t & 1) * BUF;
        char* nxt = lds + ((t + 1) & 1) * BUF;
        if (t < NSTEP - 1) {
            loadB((t + 1) * 64);                       // B(t+1) regs, in flight
            asm volatile("s_waitcnt vmcnt(5)" ::: "memory");   // A(t) landed
        } else {
            asm volatile("s_waitcnt vmcnt(0)" ::: "memory");
        }
        asm volatile("s_waitcnt lgkmcnt(0)" ::: "memory");     // publish ds_writes
        __builtin_amdgcn_s_barrier();                  // tile t complete; nxt free
        if (t < NSTEP - 1)
            stage_lds<BM, 8>(C1, K, m0, (t + 1) * 64, nxt, wid, lane);  // A(t+1)

        // compute tile t: kk-halves interleaved to keep frag regs low
        #pragma unroll
        for (int kk = 0; kk < 2; ++kk) {
            const int c = kk * 4 + lg;
            s16x8 af[MF], bfr[NF];
            #pragma unroll
            for (int f = 0; f < MF; ++f) {
                const int row = arow_base + f * 16 + lr;
                af[f] = *reinterpret_cast<const s16x8*>(cur + row * 128 + ((c ^ (row & 7)) << 4));
            }
            #pragma unroll
            for (int f = 0; f < NF; ++f) {
                const int row = brow_base + f * 16 + lr;
                bfr[f] = *reinterpret_cast<const s16x8*>(cur + ABUF + row * 128 + ((c ^ (row & 7)) << 4));
            }
            __builtin_amdgcn_s_setprio(1);
            #pragma unroll
            for (int mi = 0; mi < MF; ++mi)
                #pragma unroll
                for (int ni = 0; ni < NF; ++ni)
                    acc[mi][ni] = __builtin_amdgcn_mfma_f32_16x16x32_bf16(
                        af[mi], bfr[ni], acc[mi][ni], 0, 0, 0);
            __builtin_amdgcn_s_setprio(0);
        }

        if (t < NSTEP - 1)
            writeB(nxt + ABUF);                        // cvt+write B(t+1) (late)
    }

    // epilogue: C/D layout col = lane&15, row = (lane>>4)*4 + reg   [m89]
    #pragma unroll
    for (int mi = 0; mi < MF; ++mi)
        #pragma unroll
        for (int ni = 0; ni < NF; ++ni) {
            const int gcol = n0 + brow_base + ni * 16 + lr;
            const int grow0 = m0 + arow_base + mi * 16 + lg * 4;
            #pragma unroll
            for (int r = 0; r < 4; ++r)
                out[(size_t)(grow0 + r) * N + gcol] = acc[mi][ni][r];
        }
}

// ---------------------------------------------------------------------------

extern "C" void kernel_launch(void* const* d_in, const int* in_sizes, int n_in,
                              void* d_out, int out_size, void* d_ws, size_t ws_size,
                              hipStream_t stream) {
    const float* x = (const float*)d_in[0];     // [512,1024]
    const float* E = (const float*)d_in[1];     // [20000,512]
    const float* W = (const float*)d_in[2];     // [1024,512]
    float* out = (float*)d_out;                 // [512,20000]

    unsigned short* C1 = (unsigned short*)d_ws; // 512 KiB

    // K1: fused prep + GEMM1 (reads x, W f32 directly)
    fused_g1<<<256, 256, 0, stream>>>(x, W, C1);

    // K2: out = C1 @ E^T, 8-wave blocks, 504 launched (500 real)
    gemm2fused<<<504, 512, 0, stream>>>(C1, E, out);
}